// Round 4
// baseline (793.097 us; speedup 1.0000x reference)
//
#include <hip/hip_runtime.h>
#include <math.h>

#define DD 64      // feature dim
#define MM 128     // time points per path
#define PP 127     // increments per path

typedef float f32x2 __attribute__((ext_vector_type(2)));

#define FOR16(F) F(0) F(1) F(2) F(3) F(4) F(5) F(6) F(7) \
                 F(8) F(9) F(10) F(11) F(12) F(13) F(14) F(15)

// ---- wave64 inclusive add-scan via DPP (classic GCN sequence, ~12 VALU) ----
template<int CTRL, int RM, bool BC>
__device__ __forceinline__ float dpp_add(float x) {
    int t = __builtin_amdgcn_update_dpp(0, __float_as_int(x), CTRL, RM, 0xf, BC);
    return x + __int_as_float(t);
}
__device__ __forceinline__ float wave_incl_scan(float x) {
    x = dpp_add<0x111, 0xf, true >(x);   // row_shr:1
    x = dpp_add<0x112, 0xf, true >(x);   // row_shr:2
    x = dpp_add<0x114, 0xf, true >(x);   // row_shr:4
    x = dpp_add<0x118, 0xf, true >(x);   // row_shr:8
    x = dpp_add<0x142, 0xa, false>(x);   // row_bcast:15 -> rows 1,3
    x = dpp_add<0x143, 0xc, false>(x);   // row_bcast:31 -> rows 2,3
    return x;
}

// One wave per (gram, a, b) pair, compact grid:
//   blocks [0,2080)      gram 0 = K(X_a,X_b), a<=b (upper triangle)
//   blocks [2080,4160)   gram 1 = K(Y_a,Y_b), a<=b
//   blocks [4160,8256)   gram 2 = K(X_a,Y_b), all pairs
//
// Left-aligned Goursat rows: lane l holds KL = K[p][64s+l]. Per row p:
//   m[l]      = (s[p+1]-s[p]) * KL        (s[p] = dot(U_row[p], dV_row[q]))
//   KL_new[l] = (Kb_new - Kb_old) + KL[l] + (incl_scan(m)[l] - m[l])
// dV row lives in 32 named f32x2 VGPR pairs, PINNED INSIDE the p-loop so the
// allocator cannot rematerialize the V loads (round-2 failure mode: VGPR=48,
// FETCH 5x compulsory). Dots use v_pk_fma_f32 (2 FMA/instr).
__global__ __launch_bounds__(64, 4) void sig_goursat_kernel(
        const float* __restrict__ X, const float* __restrict__ Y,
        float* __restrict__ Kout)
{
    const int bid = blockIdx.x;
    int g, a, b;
    if (bid < 4160) {                  // symmetric grams, triangular index
        g = bid < 2080 ? 0 : 1;
        const int t = bid - g * 2080;
        float sq = sqrtf(4160.25f - 2.0f * (float)t);
        a = (int)(64.5f - sq);
        if (a < 0) a = 0; if (a > 63) a = 63;
        while (a > 0  && (a * (129 - a)) / 2 > t) --a;
        while (a < 63 && ((a + 1) * (128 - a)) / 2 <= t) ++a;
        b = a + (t - (a * (129 - a)) / 2);
    } else {
        const int t = bid - 4160;
        g = 2; a = t >> 6; b = t & 63;
    }

    const float* __restrict__ U = (g == 1 ? Y : X) + (size_t)a * (MM * DD);
    const float* __restrict__ V = (g == 0 ? X : Y) + (size_t)b * (MM * DD);

    const int lane = threadIdx.x;
    __shared__ float bnd[MM + 1];      // bnd[p] = K[p][64]

    float result = 0.0f;

    for (int s = 0; s < 2; ++s) {
        const int q  = s * 64 + lane;
        const int qa = q > 126 ? 126 : q;     // clamp (s=1,lane=63: unused cell)
        const float* __restrict__ Vr0 = V + (size_t)qa * DD;
        const float* __restrict__ Vr1 = Vr0 + DD;

        // ---- dV row: 32 named f32x2 pairs (64 VGPRs) ----
#define DVDECL(i) f32x2 dvA##i, dvB##i;
        FOR16(DVDECL)
#define DVLOAD(i) { float4 v0_ = *(const float4*)(Vr0 + 4*(i)); \
                    float4 v1_ = *(const float4*)(Vr1 + 4*(i)); \
                    dvA##i = (f32x2){v1_.x - v0_.x, v1_.y - v0_.y}; \
                    dvB##i = (f32x2){v1_.z - v0_.z, v1_.w - v0_.w}; }
        FOR16(DVLOAD)

        // packed-FMA dot step: 2 x v_pk_fma_f32, alternating acc pairs by parity
#define DOTSTEP(i) { float4 u_ = *(const float4*)(ur_ + 4*(i)); \
    f32x2 ul_ = {u_.x, u_.y}; f32x2 uh_ = {u_.z, u_.w}; \
    asm("v_pk_fma_f32 %0, %2, %3, %0\n\t" \
        "v_pk_fma_f32 %1, %4, %5, %1" \
        : "+v"(((i)&1) ? accC : accA), "+v"(((i)&1) ? accD : accB) \
        : "v"(ul_), "v"(dvA##i), "v"(uh_), "v"(dvB##i)); }
#define DOT(rowptr, out) { const float* __restrict__ ur_ = (rowptr); \
    f32x2 accA = {0.f,0.f}, accB = {0.f,0.f}, accC = {0.f,0.f}, accD = {0.f,0.f}; \
    FOR16(DOTSTEP) \
    out = ((accA.x + accA.y) + (accB.x + accB.y)) \
        + ((accC.x + accC.y) + (accD.x + accD.y)); }

        float KL    = 1.0f;    // K[0][q] = 1
        float bK    = 1.0f;    // strip 0: running K[p][64]
        float prevB = 1.0f;    // strip 1: bnd[p]
        float s0;
        DOT(U, s0)

        for (int p = 0; p < PP; ++p) {
            // PIN dv inside the loop: opaque redefinition each iteration ->
            // rematerialization impossible, must stay register-resident.
#define DVPIN_A(i) "+v"(dvA##i),
#define DVPIN_B(i) "+v"(dvB##i),
            asm volatile("" : FOR16(DVPIN_A) "+v"(KL));
            asm volatile("" : FOR16(DVPIN_B) "+v"(s0));

            float curB = 0.0f;
            if (s == 1) curB = bnd[p + 1];        // uniform LDS read
            float s1;
            DOT(U + (size_t)(p + 1) * DD, s1)
            const float m = (s1 - s0) * KL;
            s0 = s1;
            const float sc = wave_incl_scan(m);   // inclusive scan of m
            if (s == 0) {
                KL += sc - m;                     // Kb_new == Kb_old == 1
                bK += __int_as_float(__builtin_amdgcn_readlane(__float_as_int(sc), 63));
                if (lane == 0) bnd[p + 1] = bK;   // K[p+1][64] for strip 1
            } else {
                KL += (curB - prevB) + (sc - m);
                prevB = curB;
            }
        }
        if (s == 1 && lane == 63) result = KL;    // K[127][127]
    }

    if (lane == 63) Kout[(size_t)g * 4096 + a * 64 + b] = result;
}

// Deterministic weighted reduction + the mean((X0-Y0)^2) term.
__global__ void sig_reduce_kernel(const float* __restrict__ X,
                                  const float* __restrict__ Y,
                                  const float* __restrict__ Kws,
                                  float* __restrict__ out)
{
    const int t = threadIdx.x;
    double accK = 0.0, acc2 = 0.0;
    for (int i = t; i < 4096; i += 256) {
        const int a = i >> 6, b = i & 63;
        if (a <= b) {
            const double w = (a == b) ? 1.0 : 2.0;
            accK += w * (double)Kws[i];           // XX
            accK += w * (double)Kws[4096 + i];    // YY
        }
        accK -= 2.0 * (double)Kws[8192 + i];      // XY
        const float df = X[(size_t)a * (MM * DD) + b] - Y[(size_t)a * (MM * DD) + b];
        acc2 += (double)df * (double)df;
    }
    __shared__ double red[256];
    red[t] = accK / 4096.0 + acc2 / 4096.0;
    __syncthreads();
    for (int s = 128; s > 0; s >>= 1) {
        if (t < s) red[t] += red[t + s];
        __syncthreads();
    }
    if (t == 0) out[0] = (float)red[0];
}

extern "C" void kernel_launch(void* const* d_in, const int* in_sizes, int n_in,
                              void* d_out, int out_size, void* d_ws, size_t ws_size,
                              hipStream_t stream) {
    const float* X = (const float*)d_in[0];
    const float* Y = (const float*)d_in[1];
    float* Kws = (float*)d_ws;          // 3 * 4096 floats
    float* out = (float*)d_out;

    sig_goursat_kernel<<<dim3(8256), dim3(64), 0, stream>>>(X, Y, Kws);
    sig_reduce_kernel<<<dim3(1), dim3(256), 0, stream>>>(X, Y, Kws, out);
}

// Round 5
// 558.095 us; speedup vs baseline: 1.4211x; 1.4211x over previous
//
#include <hip/hip_runtime.h>
#include <math.h>

#define DD 64      // feature dim
#define MM 128     // time points per path

typedef float  f32x4v __attribute__((ext_vector_type(4)));
typedef __bf16 bf16x8 __attribute__((ext_vector_type(8)));

union FragU { unsigned int u[4]; bf16x8 v; };

// RNE f32x2 -> packed bf16x2 (low half from %1, high half from %2)
__device__ __forceinline__ unsigned cvtpk(float lo, float hi) {
    unsigned r;
    asm("v_cvt_pk_bf16_f32 %0, %1, %2" : "=v"(r) : "v"(lo), "v"(hi));
    return r;
}

// bf16 frag of (row1 - row0), 8 consecutive floats, hi part only
__device__ __forceinline__ bf16x8 dfrag_hi(const float* __restrict__ r0,
                                           const float* __restrict__ r1) {
    f32x4v a0 = *(const f32x4v*)r0, a1 = *(const f32x4v*)(r0 + 4);
    f32x4v b0 = *(const f32x4v*)r1, b1 = *(const f32x4v*)(r1 + 4);
    FragU f;
    f.u[0] = cvtpk(b0.x - a0.x, b0.y - a0.y);
    f.u[1] = cvtpk(b0.z - a0.z, b0.w - a0.w);
    f.u[2] = cvtpk(b1.x - a1.x, b1.y - a1.y);
    f.u[3] = cvtpk(b1.z - a1.z, b1.w - a1.w);
    return f.v;
}

// bf16 hi + lo (residual) frags of (row1 - row0)
__device__ __forceinline__ void dfrag_hilo(const float* __restrict__ r0,
                                           const float* __restrict__ r1,
                                           bf16x8& hi, bf16x8& lo) {
    f32x4v a0 = *(const f32x4v*)r0, a1 = *(const f32x4v*)(r0 + 4);
    f32x4v b0 = *(const f32x4v*)r1, b1 = *(const f32x4v*)(r1 + 4);
    float d0 = b0.x - a0.x, d1 = b0.y - a0.y, d2 = b0.z - a0.z, d3 = b0.w - a0.w;
    float d4 = b1.x - a1.x, d5 = b1.y - a1.y, d6 = b1.z - a1.z, d7 = b1.w - a1.w;
    FragU H, L;
    H.u[0] = cvtpk(d0, d1); H.u[1] = cvtpk(d2, d3);
    H.u[2] = cvtpk(d4, d5); H.u[3] = cvtpk(d6, d7);
    float e0 = d0 - __uint_as_float(H.u[0] << 16);
    float e1 = d1 - __uint_as_float(H.u[0] & 0xffff0000u);
    float e2 = d2 - __uint_as_float(H.u[1] << 16);
    float e3 = d3 - __uint_as_float(H.u[1] & 0xffff0000u);
    float e4 = d4 - __uint_as_float(H.u[2] << 16);
    float e5 = d5 - __uint_as_float(H.u[2] & 0xffff0000u);
    float e6 = d6 - __uint_as_float(H.u[3] << 16);
    float e7 = d7 - __uint_as_float(H.u[3] & 0xffff0000u);
    L.u[0] = cvtpk(e0, e1); L.u[1] = cvtpk(e2, e3);
    L.u[2] = cvtpk(e4, e5); L.u[3] = cvtpk(e6, e7);
    hi = H.v; lo = L.v;
}

// ---- wave64 inclusive add-scan via DPP (proven rounds 2-3) ----
template<int CTRL, int RM, bool BC>
__device__ __forceinline__ float dpp_add(float x) {
    int t = __builtin_amdgcn_update_dpp(0, __float_as_int(x), CTRL, RM, 0xf, BC);
    return x + __int_as_float(t);
}
__device__ __forceinline__ float wave_incl_scan(float x) {
    x = dpp_add<0x111, 0xf, true >(x);   // row_shr:1
    x = dpp_add<0x112, 0xf, true >(x);   // row_shr:2
    x = dpp_add<0x114, 0xf, true >(x);   // row_shr:4
    x = dpp_add<0x118, 0xf, true >(x);   // row_shr:8
    x = dpp_add<0x142, 0xa, false>(x);   // row_bcast:15 -> rows 1,3
    x = dpp_add<0x143, 0xc, false>(x);   // row_bcast:31 -> rows 2,3
    return x;
}

// One wave per (gram, a, b) pair, compact grid (triangular decode proven r2/r3).
// Per 16-row band: MFMA computes inc[16][128] (bf16 A hi+lo x B hi, fp32 acc)
// into LDS even/odd column planes; then the left-aligned Goursat scan consumes
// the band, 2 columns per lane (full 128-col rows, base K[.][0]=1, no strips):
//   m0 = incE*KL0; m1 = incO*KL1; excl = scan(m0+m1)-(m0+m1);
//   KL1 += excl + m0; KL0 += excl.
// Phantom col 127 / row 127 never feed any consumed value (clamped loads).
__global__ __launch_bounds__(64, 4) void sig_goursat_kernel(
        const float* __restrict__ X, const float* __restrict__ Y,
        float* __restrict__ Kout)
{
    const int bid = blockIdx.x;
    int g, a, b;
    if (bid < 4160) {                  // symmetric grams, triangular index
        g = bid < 2080 ? 0 : 1;
        const int t = bid - g * 2080;
        float sq = sqrtf(4160.25f - 2.0f * (float)t);
        a = (int)(64.5f - sq);
        if (a < 0) a = 0; if (a > 63) a = 63;
        while (a > 0  && (a * (129 - a)) / 2 > t) --a;
        while (a < 63 && ((a + 1) * (128 - a)) / 2 <= t) ++a;
        b = a + (t - (a * (129 - a)) / 2);
    } else {
        const int t = bid - 4160;
        g = 2; a = t >> 6; b = t & 63;
    }

    const float* __restrict__ U = (g == 1 ? Y : X) + (size_t)a * (MM * DD);
    const float* __restrict__ V = (g == 0 ? X : Y) + (size_t)b * (MM * DD);

    const int lane = threadIdx.x;
    const int l15  = lane & 15;
    const int k8   = (lane >> 4) * 8;         // k-offset of this lane's frag elems
    const int rowg = (lane >> 4) * 4;         // C/D row group base

    // inc LDS: even cols at word row*65+half, odd cols at 1048 + row*65 + half
    __shared__ float incL[2100];

    float KL0 = 1.0f, KL1 = 1.0f;             // K[0][2l], K[0][2l+1] = 1

    const int wbase = rowg * 65 + (l15 >> 1) + ((lane & 1) ? 1048 : 0);

    for (int band = 0; band < 8; ++band) {
        // ---- A frags for this band: rows p = band*16 + (lane&15), hi+lo ----
        int arow = band * 16 + l15; if (arow > 126) arow = 126;   // clamp p=127
        const float* ap = U + (size_t)arow * DD + k8;
        bf16x8 ahi0, alo0, ahi1, alo1;
        dfrag_hilo(ap,      ap + DD,      ahi0, alo0);            // k-half 0
        dfrag_hilo(ap + 32, ap + DD + 32, ahi1, alo1);            // k-half 1

        // ---- inc tile: 8 col-tiles of 16 ----
        for (int ct = 0; ct < 8; ++ct) {
            int brow = ct * 16 + l15; if (brow > 126) brow = 126; // clamp q=127
            const float* vp = V + (size_t)brow * DD + k8;
            bf16x8 bhi0 = dfrag_hi(vp,      vp + DD);
            bf16x8 bhi1 = dfrag_hi(vp + 32, vp + DD + 32);
            f32x4v acc = {0.f, 0.f, 0.f, 0.f};
            acc = __builtin_amdgcn_mfma_f32_16x16x32_bf16(ahi0, bhi0, acc, 0, 0, 0);
            acc = __builtin_amdgcn_mfma_f32_16x16x32_bf16(alo0, bhi0, acc, 0, 0, 0);
            acc = __builtin_amdgcn_mfma_f32_16x16x32_bf16(ahi1, bhi1, acc, 0, 0, 0);
            acc = __builtin_amdgcn_mfma_f32_16x16x32_bf16(alo1, bhi1, acc, 0, 0, 0);
            // C/D: col = ct*16 + (lane&15), row = rowg + r  [HW-verified layout]
            const int w = wbase + ct * 8;
            incL[w]       = acc[0];
            incL[w + 65]  = acc[1];
            incL[w + 130] = acc[2];
            incL[w + 195] = acc[3];
        }

        // ---- Goursat scan over the band's rows (single wave: lgkmcnt orders) ----
        for (int r = 0; r < 16; ++r) {
            const int p = band * 16 + r;
            if (p > 126) break;                         // row 127 is phantom
            const float iE = incL[r * 65 + lane];        // inc[p][2*lane]
            const float iO = incL[1048 + r * 65 + lane]; // inc[p][2*lane+1]
            const float m0 = iE * KL0;
            const float m1 = iO * KL1;
            const float t  = m0 + m1;
            const float S  = wave_incl_scan(t);
            const float excl = S - t;
            KL1 += excl + m0;
            KL0 += excl;
        }
    }

    if (lane == 63) Kout[(size_t)g * 4096 + a * 64 + b] = KL1;   // K[127][127]
}

// Deterministic weighted reduction + the mean((X0-Y0)^2) term.
__global__ void sig_reduce_kernel(const float* __restrict__ X,
                                  const float* __restrict__ Y,
                                  const float* __restrict__ Kws,
                                  float* __restrict__ out)
{
    const int t = threadIdx.x;
    double accK = 0.0, acc2 = 0.0;
    for (int i = t; i < 4096; i += 256) {
        const int a = i >> 6, b = i & 63;
        if (a <= b) {
            const double w = (a == b) ? 1.0 : 2.0;
            accK += w * (double)Kws[i];           // XX
            accK += w * (double)Kws[4096 + i];    // YY
        }
        accK -= 2.0 * (double)Kws[8192 + i];      // XY
        const float df = X[(size_t)a * (MM * DD) + b] - Y[(size_t)a * (MM * DD) + b];
        acc2 += (double)df * (double)df;
    }
    __shared__ double red[256];
    red[t] = accK / 4096.0 + acc2 / 4096.0;
    __syncthreads();
    for (int s = 128; s > 0; s >>= 1) {
        if (t < s) red[t] += red[t + s];
        __syncthreads();
    }
    if (t == 0) out[0] = (float)red[0];
}

extern "C" void kernel_launch(void* const* d_in, const int* in_sizes, int n_in,
                              void* d_out, int out_size, void* d_ws, size_t ws_size,
                              hipStream_t stream) {
    const float* X = (const float*)d_in[0];
    const float* Y = (const float*)d_in[1];
    float* Kws = (float*)d_ws;          // 3 * 4096 floats
    float* out = (float*)d_out;

    sig_goursat_kernel<<<dim3(8256), dim3(64), 0, stream>>>(X, Y, Kws);
    sig_reduce_kernel<<<dim3(1), dim3(256), 0, stream>>>(X, Y, Kws, out);
}

// Round 6
// 148.004 us; speedup vs baseline: 5.3586x; 3.7708x over previous
//
#include <hip/hip_runtime.h>
#include <math.h>

#define DD 64      // feature dim
#define MM 128     // time points per path

typedef float  f32x4v __attribute__((ext_vector_type(4)));
typedef __bf16 bf16x8 __attribute__((ext_vector_type(8)));

#define FOR8(F) F(0) F(1) F(2) F(3) F(4) F(5) F(6) F(7)

union FragU { unsigned int u[4]; bf16x8 v; };

// RNE f32x2 -> packed bf16x2
__device__ __forceinline__ unsigned cvtpk(float lo, float hi) {
    unsigned r;
    asm("v_cvt_pk_bf16_f32 %0, %1, %2" : "=v"(r) : "v"(lo), "v"(hi));
    return r;
}

// bf16 frag of (row1 - row0), 8 consecutive floats, hi part only
__device__ __forceinline__ bf16x8 dfrag_hi(const float* __restrict__ r0,
                                           const float* __restrict__ r1) {
    f32x4v a0 = *(const f32x4v*)r0, a1 = *(const f32x4v*)(r0 + 4);
    f32x4v b0 = *(const f32x4v*)r1, b1 = *(const f32x4v*)(r1 + 4);
    FragU f;
    f.u[0] = cvtpk(b0.x - a0.x, b0.y - a0.y);
    f.u[1] = cvtpk(b0.z - a0.z, b0.w - a0.w);
    f.u[2] = cvtpk(b1.x - a1.x, b1.y - a1.y);
    f.u[3] = cvtpk(b1.z - a1.z, b1.w - a1.w);
    return f.v;
}

// bf16 hi + lo (residual) frags of (row1 - row0)
__device__ __forceinline__ void dfrag_hilo(const float* __restrict__ r0,
                                           const float* __restrict__ r1,
                                           bf16x8& hi, bf16x8& lo) {
    f32x4v a0 = *(const f32x4v*)r0, a1 = *(const f32x4v*)(r0 + 4);
    f32x4v b0 = *(const f32x4v*)r1, b1 = *(const f32x4v*)(r1 + 4);
    float d0 = b0.x - a0.x, d1 = b0.y - a0.y, d2 = b0.z - a0.z, d3 = b0.w - a0.w;
    float d4 = b1.x - a1.x, d5 = b1.y - a1.y, d6 = b1.z - a1.z, d7 = b1.w - a1.w;
    FragU H, L;
    H.u[0] = cvtpk(d0, d1); H.u[1] = cvtpk(d2, d3);
    H.u[2] = cvtpk(d4, d5); H.u[3] = cvtpk(d6, d7);
    float e0 = d0 - __uint_as_float(H.u[0] << 16);
    float e1 = d1 - __uint_as_float(H.u[0] & 0xffff0000u);
    float e2 = d2 - __uint_as_float(H.u[1] << 16);
    float e3 = d3 - __uint_as_float(H.u[1] & 0xffff0000u);
    float e4 = d4 - __uint_as_float(H.u[2] << 16);
    float e5 = d5 - __uint_as_float(H.u[2] & 0xffff0000u);
    float e6 = d6 - __uint_as_float(H.u[3] << 16);
    float e7 = d7 - __uint_as_float(H.u[3] & 0xffff0000u);
    L.u[0] = cvtpk(e0, e1); L.u[1] = cvtpk(e2, e3);
    L.u[2] = cvtpk(e4, e5); L.u[3] = cvtpk(e6, e7);
    hi = H.v; lo = L.v;
}

// ---- wave64 inclusive add-scan via DPP (proven rounds 2-5) ----
template<int CTRL, int RM, bool BC>
__device__ __forceinline__ float dpp_add(float x) {
    int t = __builtin_amdgcn_update_dpp(0, __float_as_int(x), CTRL, RM, 0xf, BC);
    return x + __int_as_float(t);
}
__device__ __forceinline__ float wave_incl_scan(float x) {
    x = dpp_add<0x111, 0xf, true >(x);   // row_shr:1
    x = dpp_add<0x112, 0xf, true >(x);   // row_shr:2
    x = dpp_add<0x114, 0xf, true >(x);   // row_shr:4
    x = dpp_add<0x118, 0xf, true >(x);   // row_shr:8
    x = dpp_add<0x142, 0xa, false>(x);   // row_bcast:15 -> rows 1,3
    x = dpp_add<0x143, 0xc, false>(x);   // row_bcast:31 -> rows 2,3
    return x;
}

// One wave per (gram, a, b) pair, compact grid (decode proven r2-r5).
// V-side bf16 fragments (all 8 col-tiles x 2 k-halves) are built ONCE per
// pair into 16 STATICALLY-NAMED bf16x8 registers (64 VGPRs) -- loop-invariant
// across the 8 row-bands, so the MFMA inner loop touches no global memory.
// Per band: A frags (hi+lo) from global, 8x{4 MFMA + 4 LDS writes}, then the
// DPP-scan Goursat consumes 16 rows (2 cols/lane). inc LDS: even cols at
// word r*65+l, odd cols at 1040 + r*65 + l (2-way banks everywhere = free).
__global__ __launch_bounds__(64, 4) void sig_goursat_kernel(
        const float* __restrict__ X, const float* __restrict__ Y,
        float* __restrict__ Kout)
{
    const int bid = blockIdx.x;
    int g, a, b;
    if (bid < 4160) {                  // symmetric grams, triangular index
        g = bid < 2080 ? 0 : 1;
        const int t = bid - g * 2080;
        float sq = sqrtf(4160.25f - 2.0f * (float)t);
        a = (int)(64.5f - sq);
        if (a < 0) a = 0; if (a > 63) a = 63;
        while (a > 0  && (a * (129 - a)) / 2 > t) --a;
        while (a < 63 && ((a + 1) * (128 - a)) / 2 <= t) ++a;
        b = a + (t - (a * (129 - a)) / 2);
    } else {
        const int t = bid - 4160;
        g = 2; a = t >> 6; b = t & 63;
    }

    const float* __restrict__ U = (g == 1 ? Y : X) + (size_t)a * (MM * DD);
    const float* __restrict__ V = (g == 0 ? X : Y) + (size_t)b * (MM * DD);

    const int lane = threadIdx.x;
    const int l15  = lane & 15;
    const int k8   = (lane >> 4) * 8;         // k-offset of this lane's frag
    const int rowg = (lane >> 4) * 4;         // C/D row group base

    __shared__ float incL[2080];   // even plane [16][65] @0, odd plane @1040

    // ---- B-frag register table: 16 named bf16x8 (64 VGPRs), built once ----
#define TBDECL(ct) bf16x8 tb0_##ct, tb1_##ct;
    FOR8(TBDECL)
#define TBUILD(ct) { int brow_ = ct * 16 + l15; if (brow_ > 126) brow_ = 126; \
        const float* vp_ = V + (size_t)brow_ * DD + k8; \
        tb0_##ct = dfrag_hi(vp_,      vp_ + DD); \
        tb1_##ct = dfrag_hi(vp_ + 32, vp_ + DD + 32); }
    FOR8(TBUILD)

    float KL0 = 1.0f, KL1 = 1.0f;             // K[0][2l], K[0][2l+1] = 1
    const int wbase = rowg * 65 + (l15 >> 1) + ((lane & 1) ? 1040 : 0);

#define CTSTEP(ct) { f32x4v acc = {0.f, 0.f, 0.f, 0.f}; \
        acc = __builtin_amdgcn_mfma_f32_16x16x32_bf16(ahi0, tb0_##ct, acc, 0, 0, 0); \
        acc = __builtin_amdgcn_mfma_f32_16x16x32_bf16(alo0, tb0_##ct, acc, 0, 0, 0); \
        acc = __builtin_amdgcn_mfma_f32_16x16x32_bf16(ahi1, tb1_##ct, acc, 0, 0, 0); \
        acc = __builtin_amdgcn_mfma_f32_16x16x32_bf16(alo1, tb1_##ct, acc, 0, 0, 0); \
        const int w_ = wbase + ct * 8; \
        incL[w_]       = acc[0]; \
        incL[w_ + 65]  = acc[1]; \
        incL[w_ + 130] = acc[2]; \
        incL[w_ + 195] = acc[3]; }

    for (int band = 0; band < 8; ++band) {
        // ---- A frags: rows p = band*16 + l15 (clamped), hi + lo residual ----
        int arow = band * 16 + l15; if (arow > 126) arow = 126;
        const float* ap = U + (size_t)arow * DD + k8;
        bf16x8 ahi0, alo0, ahi1, alo1;
        dfrag_hilo(ap,      ap + DD,      ahi0, alo0);
        dfrag_hilo(ap + 32, ap + DD + 32, ahi1, alo1);

        FOR8(CTSTEP)   // inc[16][128] for this band -> LDS

        // ---- Goursat scan over the band's rows ----
        const int rmax = (band == 7) ? 15 : 16;   // p=127 is phantom
        for (int r = 0; r < rmax; ++r) {
            const float iE = incL[r * 65 + lane];         // inc[p][2*lane]
            const float iO = incL[1040 + r * 65 + lane];  // inc[p][2*lane+1]
            const float m0 = iE * KL0;
            const float m1 = iO * KL1;
            const float t  = m0 + m1;
            const float S  = wave_incl_scan(t);
            const float excl = S - t;
            KL1 += excl + m0;
            KL0 += excl;
        }
    }

    if (lane == 63) Kout[(size_t)g * 4096 + a * 64 + b] = KL1;   // K[127][127]
}

// Deterministic weighted reduction + the mean((X0-Y0)^2) term.
__global__ void sig_reduce_kernel(const float* __restrict__ X,
                                  const float* __restrict__ Y,
                                  const float* __restrict__ Kws,
                                  float* __restrict__ out)
{
    const int t = threadIdx.x;
    double accK = 0.0, acc2 = 0.0;
    for (int i = t; i < 4096; i += 256) {
        const int a = i >> 6, b = i & 63;
        if (a <= b) {
            const double w = (a == b) ? 1.0 : 2.0;
            accK += w * (double)Kws[i];           // XX
            accK += w * (double)Kws[4096 + i];    // YY
        }
        accK -= 2.0 * (double)Kws[8192 + i];      // XY
        const float df = X[(size_t)a * (MM * DD) + b] - Y[(size_t)a * (MM * DD) + b];
        acc2 += (double)df * (double)df;
    }
    __shared__ double red[256];
    red[t] = accK / 4096.0 + acc2 / 4096.0;
    __syncthreads();
    for (int s = 128; s > 0; s >>= 1) {
        if (t < s) red[t] += red[t + s];
        __syncthreads();
    }
    if (t == 0) out[0] = (float)red[0];
}

extern "C" void kernel_launch(void* const* d_in, const int* in_sizes, int n_in,
                              void* d_out, int out_size, void* d_ws, size_t ws_size,
                              hipStream_t stream) {
    const float* X = (const float*)d_in[0];
    const float* Y = (const float*)d_in[1];
    float* Kws = (float*)d_ws;          // 3 * 4096 floats
    float* out = (float*)d_out;

    sig_goursat_kernel<<<dim3(8256), dim3(64), 0, stream>>>(X, Y, Kws);
    sig_reduce_kernel<<<dim3(1), dim3(256), 0, stream>>>(X, Y, Kws, out);
}

// Round 7
// 143.873 us; speedup vs baseline: 5.5125x; 1.0287x over previous
//
#include <hip/hip_runtime.h>
#include <math.h>

#define DD 64      // feature dim
#define MM 128     // time points per path

typedef float  f32x4v __attribute__((ext_vector_type(4)));
typedef __bf16 bf16x8 __attribute__((ext_vector_type(8)));

#define FOR8(F) F(0) F(1) F(2) F(3) F(4) F(5) F(6) F(7)

union FragU { unsigned int u[4]; bf16x8 v; };

// RNE f32x2 -> packed bf16x2
__device__ __forceinline__ unsigned cvtpk(float lo, float hi) {
    unsigned r;
    asm("v_cvt_pk_bf16_f32 %0, %1, %2" : "=v"(r) : "v"(lo), "v"(hi));
    return r;
}

// bf16 frag of (row1 - row0), 8 consecutive floats, hi part only
__device__ __forceinline__ bf16x8 dfrag_hi(const float* __restrict__ r0,
                                           const float* __restrict__ r1) {
    f32x4v a0 = *(const f32x4v*)r0, a1 = *(const f32x4v*)(r0 + 4);
    f32x4v b0 = *(const f32x4v*)r1, b1 = *(const f32x4v*)(r1 + 4);
    FragU f;
    f.u[0] = cvtpk(b0.x - a0.x, b0.y - a0.y);
    f.u[1] = cvtpk(b0.z - a0.z, b0.w - a0.w);
    f.u[2] = cvtpk(b1.x - a1.x, b1.y - a1.y);
    f.u[3] = cvtpk(b1.z - a1.z, b1.w - a1.w);
    return f.v;
}

// bf16 hi + lo (residual) frags of (row1 - row0)
__device__ __forceinline__ void dfrag_hilo(const float* __restrict__ r0,
                                           const float* __restrict__ r1,
                                           bf16x8& hi, bf16x8& lo) {
    f32x4v a0 = *(const f32x4v*)r0, a1 = *(const f32x4v*)(r0 + 4);
    f32x4v b0 = *(const f32x4v*)r1, b1 = *(const f32x4v*)(r1 + 4);
    float d0 = b0.x - a0.x, d1 = b0.y - a0.y, d2 = b0.z - a0.z, d3 = b0.w - a0.w;
    float d4 = b1.x - a1.x, d5 = b1.y - a1.y, d6 = b1.z - a1.z, d7 = b1.w - a1.w;
    FragU H, L;
    H.u[0] = cvtpk(d0, d1); H.u[1] = cvtpk(d2, d3);
    H.u[2] = cvtpk(d4, d5); H.u[3] = cvtpk(d6, d7);
    float e0 = d0 - __uint_as_float(H.u[0] << 16);
    float e1 = d1 - __uint_as_float(H.u[0] & 0xffff0000u);
    float e2 = d2 - __uint_as_float(H.u[1] << 16);
    float e3 = d3 - __uint_as_float(H.u[1] & 0xffff0000u);
    float e4 = d4 - __uint_as_float(H.u[2] << 16);
    float e5 = d5 - __uint_as_float(H.u[2] & 0xffff0000u);
    float e6 = d6 - __uint_as_float(H.u[3] << 16);
    float e7 = d7 - __uint_as_float(H.u[3] & 0xffff0000u);
    L.u[0] = cvtpk(e0, e1); L.u[1] = cvtpk(e2, e3);
    L.u[2] = cvtpk(e4, e5); L.u[3] = cvtpk(e6, e7);
    hi = H.v; lo = L.v;
}

// ---- wave64 inclusive add-scan via DPP (proven rounds 2-6) ----
template<int CTRL, int RM, bool BC>
__device__ __forceinline__ float dpp_add(float x) {
    int t = __builtin_amdgcn_update_dpp(0, __float_as_int(x), CTRL, RM, 0xf, BC);
    return x + __int_as_float(t);
}
__device__ __forceinline__ float wave_incl_scan(float x) {
    x = dpp_add<0x111, 0xf, true >(x);   // row_shr:1
    x = dpp_add<0x112, 0xf, true >(x);   // row_shr:2
    x = dpp_add<0x114, 0xf, true >(x);   // row_shr:4
    x = dpp_add<0x118, 0xf, true >(x);   // row_shr:8
    x = dpp_add<0x142, 0xa, false>(x);   // row_bcast:15 -> rows 1,3
    x = dpp_add<0x143, 0xc, false>(x);   // row_bcast:31 -> rows 2,3
    return x;
}

// One wave per (gram, a, b) pair, compact grid (decode proven r2-r6).
// V-side bf16 fragments live in 16 statically-named bf16x8 registers built
// once per pair; per band: A frags (hi+lo) from global, 8x{4 MFMA + 4 LDS
// writes}, then the DPP-scan Goursat consumes 16 rows (2 cols/lane).
//
// ROUND 6 FIX: __launch_bounds__(64,4) capped the unified VGPR+AGPR file at
// 128 regs/wave while the live set is ~160 -> the allocator spilled to
// scratch (WRITE_SIZE 8.5 MB, 10x wall-time expansion). (64,2) caps at 256:
// no spill, occupancy unchanged (reg-file limited at ~12 waves/CU either way).
__global__ __launch_bounds__(64, 2) void sig_goursat_kernel(
        const float* __restrict__ X, const float* __restrict__ Y,
        float* __restrict__ Kout)
{
    const int bid = blockIdx.x;
    int g, a, b;
    if (bid < 4160) {                  // symmetric grams, triangular index
        g = bid < 2080 ? 0 : 1;
        const int t = bid - g * 2080;
        float sq = sqrtf(4160.25f - 2.0f * (float)t);
        a = (int)(64.5f - sq);
        if (a < 0) a = 0; if (a > 63) a = 63;
        while (a > 0  && (a * (129 - a)) / 2 > t) --a;
        while (a < 63 && ((a + 1) * (128 - a)) / 2 <= t) ++a;
        b = a + (t - (a * (129 - a)) / 2);
    } else {
        const int t = bid - 4160;
        g = 2; a = t >> 6; b = t & 63;
    }

    const float* __restrict__ U = (g == 1 ? Y : X) + (size_t)a * (MM * DD);
    const float* __restrict__ V = (g == 0 ? X : Y) + (size_t)b * (MM * DD);

    const int lane = threadIdx.x;
    const int l15  = lane & 15;
    const int k8   = (lane >> 4) * 8;         // k-offset of this lane's frag
    const int rowg = (lane >> 4) * 4;         // C/D row group base

    __shared__ float incL[2080];   // even plane [16][65] @0, odd plane @1040

    // ---- B-frag register table: 16 named bf16x8 (64 VGPRs), built once ----
#define TBDECL(ct) bf16x8 tb0_##ct, tb1_##ct;
    FOR8(TBDECL)
#define TBUILD(ct) { int brow_ = ct * 16 + l15; if (brow_ > 126) brow_ = 126; \
        const float* vp_ = V + (size_t)brow_ * DD + k8; \
        tb0_##ct = dfrag_hi(vp_,      vp_ + DD); \
        tb1_##ct = dfrag_hi(vp_ + 32, vp_ + DD + 32); }
    FOR8(TBUILD)

    float KL0 = 1.0f, KL1 = 1.0f;             // K[0][2l], K[0][2l+1] = 1
    const int wbase = rowg * 65 + (l15 >> 1) + ((lane & 1) ? 1040 : 0);

#define CTSTEP(ct) { f32x4v acc = {0.f, 0.f, 0.f, 0.f}; \
        acc = __builtin_amdgcn_mfma_f32_16x16x32_bf16(ahi0, tb0_##ct, acc, 0, 0, 0); \
        acc = __builtin_amdgcn_mfma_f32_16x16x32_bf16(alo0, tb0_##ct, acc, 0, 0, 0); \
        acc = __builtin_amdgcn_mfma_f32_16x16x32_bf16(ahi1, tb1_##ct, acc, 0, 0, 0); \
        acc = __builtin_amdgcn_mfma_f32_16x16x32_bf16(alo1, tb1_##ct, acc, 0, 0, 0); \
        const int w_ = wbase + ct * 8; \
        incL[w_]       = acc[0]; \
        incL[w_ + 65]  = acc[1]; \
        incL[w_ + 130] = acc[2]; \
        incL[w_ + 195] = acc[3]; }

    for (int band = 0; band < 8; ++band) {
        // ---- A frags: rows p = band*16 + l15 (clamped), hi + lo residual ----
        int arow = band * 16 + l15; if (arow > 126) arow = 126;
        const float* ap = U + (size_t)arow * DD + k8;
        bf16x8 ahi0, alo0, ahi1, alo1;
        dfrag_hilo(ap,      ap + DD,      ahi0, alo0);
        dfrag_hilo(ap + 32, ap + DD + 32, ahi1, alo1);

        FOR8(CTSTEP)   // inc[16][128] for this band -> LDS

        // ---- Goursat scan over the band's rows ----
        const int rmax = (band == 7) ? 15 : 16;   // p=127 is phantom
        for (int r = 0; r < rmax; ++r) {
            const float iE = incL[r * 65 + lane];         // inc[p][2*lane]
            const float iO = incL[1040 + r * 65 + lane];  // inc[p][2*lane+1]
            const float m0 = iE * KL0;
            const float m1 = iO * KL1;
            const float t  = m0 + m1;
            const float S  = wave_incl_scan(t);
            const float excl = S - t;
            KL1 += excl + m0;
            KL0 += excl;
        }
    }

    if (lane == 63) Kout[(size_t)g * 4096 + a * 64 + b] = KL1;   // K[127][127]
}

// Deterministic weighted reduction + the mean((X0-Y0)^2) term.
__global__ void sig_reduce_kernel(const float* __restrict__ X,
                                  const float* __restrict__ Y,
                                  const float* __restrict__ Kws,
                                  float* __restrict__ out)
{
    const int t = threadIdx.x;
    double accK = 0.0, acc2 = 0.0;
    for (int i = t; i < 4096; i += 256) {
        const int a = i >> 6, b = i & 63;
        if (a <= b) {
            const double w = (a == b) ? 1.0 : 2.0;
            accK += w * (double)Kws[i];           // XX
            accK += w * (double)Kws[4096 + i];    // YY
        }
        accK -= 2.0 * (double)Kws[8192 + i];      // XY
        const float df = X[(size_t)a * (MM * DD) + b] - Y[(size_t)a * (MM * DD) + b];
        acc2 += (double)df * (double)df;
    }
    __shared__ double red[256];
    red[t] = accK / 4096.0 + acc2 / 4096.0;
    __syncthreads();
    for (int s = 128; s > 0; s >>= 1) {
        if (t < s) red[t] += red[t + s];
        __syncthreads();
    }
    if (t == 0) out[0] = (float)red[0];
}

extern "C" void kernel_launch(void* const* d_in, const int* in_sizes, int n_in,
                              void* d_out, int out_size, void* d_ws, size_t ws_size,
                              hipStream_t stream) {
    const float* X = (const float*)d_in[0];
    const float* Y = (const float*)d_in[1];
    float* Kws = (float*)d_ws;          // 3 * 4096 floats
    float* out = (float*)d_out;

    sig_goursat_kernel<<<dim3(8256), dim3(64), 0, stream>>>(X, Y, Kws);
    sig_reduce_kernel<<<dim3(1), dim3(256), 0, stream>>>(X, Y, Kws, out);
}

// Round 8
// 138.554 us; speedup vs baseline: 5.7241x; 1.0384x over previous
//
#include <hip/hip_runtime.h>
#include <math.h>

#define DD 64      // feature dim
#define MM 128     // time points per path
#define RS 133     // inc LDS row stride (words): banks (r*5+lane)%32 -> exact 2-way, free
#define OD 66      // odd-column plane offset within a row

typedef float  f32x4v __attribute__((ext_vector_type(4)));
typedef __bf16 bf16x8 __attribute__((ext_vector_type(8)));

#define FOR8(F) F(0) F(1) F(2) F(3) F(4) F(5) F(6) F(7)

union FragU { unsigned int u[4]; bf16x8 v; };

// RNE f32x2 -> packed bf16x2
__device__ __forceinline__ unsigned cvtpk(float lo, float hi) {
    unsigned r;
    asm("v_cvt_pk_bf16_f32 %0, %1, %2" : "=v"(r) : "v"(lo), "v"(hi));
    return r;
}

// bf16 frag of (row1 - row0), 8 consecutive floats, hi part only
__device__ __forceinline__ bf16x8 dfrag_hi(const float* __restrict__ r0,
                                           const float* __restrict__ r1) {
    float4 a0 = *(const float4*)r0, a1 = *(const float4*)(r0 + 4);
    float4 b0 = *(const float4*)r1, b1 = *(const float4*)(r1 + 4);
    FragU f;
    f.u[0] = cvtpk(b0.x - a0.x, b0.y - a0.y);
    f.u[1] = cvtpk(b0.z - a0.z, b0.w - a0.w);
    f.u[2] = cvtpk(b1.x - a1.x, b1.y - a1.y);
    f.u[3] = cvtpk(b1.z - a1.z, b1.w - a1.w);
    return f.v;
}

// bf16 hi + lo (residual) frags of (b - a), operands already in registers
__device__ __forceinline__ void dfrag_hilo4(float4 a0, float4 a1,
                                            float4 b0, float4 b1,
                                            bf16x8& hi, bf16x8& lo) {
    float d0 = b0.x - a0.x, d1 = b0.y - a0.y, d2 = b0.z - a0.z, d3 = b0.w - a0.w;
    float d4 = b1.x - a1.x, d5 = b1.y - a1.y, d6 = b1.z - a1.z, d7 = b1.w - a1.w;
    FragU H, L;
    H.u[0] = cvtpk(d0, d1); H.u[1] = cvtpk(d2, d3);
    H.u[2] = cvtpk(d4, d5); H.u[3] = cvtpk(d6, d7);
    float e0 = d0 - __uint_as_float(H.u[0] << 16);
    float e1 = d1 - __uint_as_float(H.u[0] & 0xffff0000u);
    float e2 = d2 - __uint_as_float(H.u[1] << 16);
    float e3 = d3 - __uint_as_float(H.u[1] & 0xffff0000u);
    float e4 = d4 - __uint_as_float(H.u[2] << 16);
    float e5 = d5 - __uint_as_float(H.u[2] & 0xffff0000u);
    float e6 = d6 - __uint_as_float(H.u[3] << 16);
    float e7 = d7 - __uint_as_float(H.u[3] & 0xffff0000u);
    L.u[0] = cvtpk(e0, e1); L.u[1] = cvtpk(e2, e3);
    L.u[2] = cvtpk(e4, e5); L.u[3] = cvtpk(e6, e7);
    hi = H.v; lo = L.v;
}

// ---- wave64 inclusive add-scan via DPP (proven rounds 2-7) ----
template<int CTRL, int RM, bool BC>
__device__ __forceinline__ float dpp_add(float x) {
    int t = __builtin_amdgcn_update_dpp(0, __float_as_int(x), CTRL, RM, 0xf, BC);
    return x + __int_as_float(t);
}
__device__ __forceinline__ float wave_incl_scan(float x) {
    x = dpp_add<0x111, 0xf, true >(x);   // row_shr:1
    x = dpp_add<0x112, 0xf, true >(x);   // row_shr:2
    x = dpp_add<0x114, 0xf, true >(x);   // row_shr:4
    x = dpp_add<0x118, 0xf, true >(x);   // row_shr:8
    x = dpp_add<0x142, 0xa, false>(x);   // row_bcast:15 -> rows 1,3
    x = dpp_add<0x143, 0xc, false>(x);   // row_bcast:31 -> rows 2,3
    return x;
}

// One wave per (gram, a, b) pair, compact grid (decode proven r2-r7).
// B-table: 16 named bf16x8 regs built once per pair (proven r5-r7).
// ROUND 7: software-pipelined band loop to kill latency exposure (r7 counters:
// VALU 30% / MFMA 10% / 60% idle):
//   per band: cvt(prefetched A) -> 8x{4 MFMA + 4 LDS writes} ->
//             ISSUE next band's 8 raw float4 A-loads (consumed next iter;
//             latency hides under the scan) -> fully-unrolled 16-row scan
//             (15 + wave-uniform conditional) so ds_reads batch ahead of
//             the DPP chains.
// inc LDS: even col q at r*RS + q/2, odd q at r*RS + OD + q/2.
__global__ __launch_bounds__(64, 2) void sig_goursat_kernel(
        const float* __restrict__ X, const float* __restrict__ Y,
        float* __restrict__ Kout)
{
    const int bid = blockIdx.x;
    int g, a, b;
    if (bid < 4160) {                  // symmetric grams, triangular index
        g = bid < 2080 ? 0 : 1;
        const int t = bid - g * 2080;
        float sq = sqrtf(4160.25f - 2.0f * (float)t);
        a = (int)(64.5f - sq);
        if (a < 0) a = 0; if (a > 63) a = 63;
        while (a > 0  && (a * (129 - a)) / 2 > t) --a;
        while (a < 63 && ((a + 1) * (128 - a)) / 2 <= t) ++a;
        b = a + (t - (a * (129 - a)) / 2);
    } else {
        const int t = bid - 4160;
        g = 2; a = t >> 6; b = t & 63;
    }

    const float* __restrict__ U = (g == 1 ? Y : X) + (size_t)a * (MM * DD);
    const float* __restrict__ V = (g == 0 ? X : Y) + (size_t)b * (MM * DD);

    const int lane = threadIdx.x;
    const int l15  = lane & 15;
    const int k8   = (lane >> 4) * 8;         // k-offset of this lane's frag
    const int rowg = (lane >> 4) * 4;         // C/D row group base

    __shared__ float incL[16 * RS];           // 2128 words = 8512 B

    // ---- issue band-0 A-row loads FIRST (latency hides under B-table build)
    float4 pA0, pA1, pA2, pA3, pB0, pB1, pB2, pB3;
    {
        const float* ap = U + (size_t)l15 * DD + k8;      // band 0: arow = l15
        pA0 = *(const float4*)(ap);           pA1 = *(const float4*)(ap + 4);
        pA2 = *(const float4*)(ap + 32);      pA3 = *(const float4*)(ap + 36);
        pB0 = *(const float4*)(ap + DD);      pB1 = *(const float4*)(ap + DD + 4);
        pB2 = *(const float4*)(ap + DD + 32); pB3 = *(const float4*)(ap + DD + 36);
    }

    // ---- B-frag register table: 16 named bf16x8 (64 regs), built once ----
#define TBDECL(ct) bf16x8 tb0_##ct, tb1_##ct;
    FOR8(TBDECL)
#define TBUILD(ct) { int brow_ = ct * 16 + l15; if (brow_ > 126) brow_ = 126; \
        const float* vp_ = V + (size_t)brow_ * DD + k8; \
        tb0_##ct = dfrag_hi(vp_,      vp_ + DD); \
        tb1_##ct = dfrag_hi(vp_ + 32, vp_ + DD + 32); }
    FOR8(TBUILD)

    float KL0 = 1.0f, KL1 = 1.0f;             // K[0][2l], K[0][2l+1] = 1
    const int wbase = rowg * RS + ((l15 & 1) ? OD : 0) + (l15 >> 1);

#define CTSTEP(ct) { f32x4v acc = {0.f, 0.f, 0.f, 0.f}; \
        acc = __builtin_amdgcn_mfma_f32_16x16x32_bf16(ahi0, tb0_##ct, acc, 0, 0, 0); \
        acc = __builtin_amdgcn_mfma_f32_16x16x32_bf16(alo0, tb0_##ct, acc, 0, 0, 0); \
        acc = __builtin_amdgcn_mfma_f32_16x16x32_bf16(ahi1, tb1_##ct, acc, 0, 0, 0); \
        acc = __builtin_amdgcn_mfma_f32_16x16x32_bf16(alo1, tb1_##ct, acc, 0, 0, 0); \
        const int w_ = wbase + ct * 8; \
        incL[w_]          = acc[0]; \
        incL[w_ + RS]     = acc[1]; \
        incL[w_ + 2*RS]   = acc[2]; \
        incL[w_ + 3*RS]   = acc[3]; }

#define SCANROW(r) { \
        const float iE = incL[(r) * RS + lane]; \
        const float iO = incL[(r) * RS + OD + lane]; \
        const float m0 = iE * KL0; \
        const float m1 = iO * KL1; \
        const float t_ = m0 + m1; \
        const float S_ = wave_incl_scan(t_); \
        const float ex = S_ - t_; \
        KL1 += ex + m0; \
        KL0 += ex; }

    for (int band = 0; band < 8; ++band) {
        // ---- cvt prefetched A rows -> hi+lo frags (loads landed long ago) ----
        bf16x8 ahi0, alo0, ahi1, alo1;
        dfrag_hilo4(pA0, pA1, pB0, pB1, ahi0, alo0);
        dfrag_hilo4(pA2, pA3, pB2, pB3, ahi1, alo1);

        FOR8(CTSTEP)   // inc[16][128] for this band -> LDS

        // ---- issue next band's A-row loads; consumed next iteration ----
        if (band < 7) {
            int arow2 = band * 16 + 16 + l15; if (arow2 > 126) arow2 = 126;
            const float* ap2 = U + (size_t)arow2 * DD + k8;
            pA0 = *(const float4*)(ap2);           pA1 = *(const float4*)(ap2 + 4);
            pA2 = *(const float4*)(ap2 + 32);      pA3 = *(const float4*)(ap2 + 36);
            pB0 = *(const float4*)(ap2 + DD);      pB1 = *(const float4*)(ap2 + DD + 4);
            pB2 = *(const float4*)(ap2 + DD + 32); pB3 = *(const float4*)(ap2 + DD + 36);
        }

        // ---- fully-unrolled Goursat scan (p = band*16 + r; p=127 phantom) ----
        #pragma unroll
        for (int r = 0; r < 15; ++r) { SCANROW(r) }
        if (band < 7) { SCANROW(15) }
    }

    if (lane == 63) Kout[(size_t)g * 4096 + a * 64 + b] = KL1;   // K[127][127]
}

// Deterministic weighted reduction + the mean((X0-Y0)^2) term.
__global__ void sig_reduce_kernel(const float* __restrict__ X,
                                  const float* __restrict__ Y,
                                  const float* __restrict__ Kws,
                                  float* __restrict__ out)
{
    const int t = threadIdx.x;
    double accK = 0.0, acc2 = 0.0;
    for (int i = t; i < 4096; i += 256) {
        const int a = i >> 6, b = i & 63;
        if (a <= b) {
            const double w = (a == b) ? 1.0 : 2.0;
            accK += w * (double)Kws[i];           // XX
            accK += w * (double)Kws[4096 + i];    // YY
        }
        accK -= 2.0 * (double)Kws[8192 + i];      // XY
        const float df = X[(size_t)a * (MM * DD) + b] - Y[(size_t)a * (MM * DD) + b];
        acc2 += (double)df * (double)df;
    }
    __shared__ double red[256];
    red[t] = accK / 4096.0 + acc2 / 4096.0;
    __syncthreads();
    for (int s = 128; s > 0; s >>= 1) {
        if (t < s) red[t] += red[t + s];
        __syncthreads();
    }
    if (t == 0) out[0] = (float)red[0];
}

extern "C" void kernel_launch(void* const* d_in, const int* in_sizes, int n_in,
                              void* d_out, int out_size, void* d_ws, size_t ws_size,
                              hipStream_t stream) {
    const float* X = (const float*)d_in[0];
    const float* Y = (const float*)d_in[1];
    float* Kws = (float*)d_ws;          // 3 * 4096 floats
    float* out = (float*)d_out;

    sig_goursat_kernel<<<dim3(8256), dim3(64), 0, stream>>>(X, Y, Kws);
    sig_reduce_kernel<<<dim3(1), dim3(256), 0, stream>>>(X, Y, Kws, out);
}